// Round 2
// baseline (98.885 us; speedup 1.0000x reference)
//
#include <hip/hip_runtime.h>

// RASP pairwise score, N=6144 atoms, P = N(N-1)/2 pairs.
// pot tensor [K=6, T=85, T=85, D=21] fp32 = 3.64 MB (fits in per-XCD L2).
// R4: diagnostic + structural round.
//  - sorted[] lives in a module __device__ buffer: d_ws is never touched
//    (tests whether the 268MB workspace re-poison fill was in the timed path).
//  - pair kernel: NO LDS j-tile. The j-atom address is wave-uniform
//    (block-derived base + loop index), so the compiler can emit scalar
//    s_load_dwordx4 and do the w-unpack on the SALU pipe, freeing VALU issue
//    slots; removes ds_read + the staging __syncthreads entirely.
//  - sort: int4-vectorized histogram pass.
// Carried from R3 (verified passing): sentinel coords subsume type-validity
// and bounds checks; w packs res<<11 | key*21; padded sorted[].

#define T_TYPES 85
#define D_BINS 21
#define KSTRIDE (T_TYPES * T_TYPES * D_BINS)  // 151725
#define NKEYS 86                              // 85 types + 1 invalid bin
#define TILE 128
#define PAIR_THREADS 256
#define JCHUNK 64                             // TILE / (PAIR_THREADS/TILE)
#define MAXN 8192

__device__ float4 g_sorted[MAXN];

// One block: zero out scalar, counting-sort by type key, write packed float4
// (xyz coords, w = res<<11 | key*21), pad to npad with far-apart sentinels.
__global__ __launch_bounds__(1024) void sort_kernel(const float* __restrict__ coords,
                                                    const int* __restrict__ res_ids,
                                                    const int* __restrict__ types,
                                                    int n, int npad,
                                                    float* __restrict__ out) {
    __shared__ int hist[NKEYS];
    __shared__ int offs[NKEYS];
    int tid = threadIdx.x;
    if (tid < NKEYS) hist[tid] = 0;
    if (tid == 0) *out = 0.0f;
    __syncthreads();
    // histogram, int4-vectorized (tail loop for generality)
    int n4 = n >> 2;
    for (int i = tid; i < n4; i += 1024) {
        int4 tv = ((const int4*)types)[i];
        atomicAdd(&hist[(tv.x < 0) ? (NKEYS - 1) : tv.x], 1);
        atomicAdd(&hist[(tv.y < 0) ? (NKEYS - 1) : tv.y], 1);
        atomicAdd(&hist[(tv.z < 0) ? (NKEYS - 1) : tv.z], 1);
        atomicAdd(&hist[(tv.w < 0) ? (NKEYS - 1) : tv.w], 1);
    }
    for (int i = (n4 << 2) + tid; i < n; i += 1024) {
        int t = types[i];
        atomicAdd(&hist[(t < 0) ? (NKEYS - 1) : t], 1);
    }
    __syncthreads();
    // parallel exclusive scan over 86 bins (wave-broadcast reads)
    if (tid < NKEYS) {
        int s = 0;
#pragma unroll 1
        for (int k = 0; k < NKEYS; ++k) {
            int h = hist[k];
            s += (k < tid) ? h : 0;
        }
        offs[tid] = s;
    }
    __syncthreads();
    for (int i = tid; i < n; i += 1024) {
        int t = types[i];
        int inv = (t < 0);
        int key = inv ? (NKEYS - 1) : t;
        int pos = atomicAdd(&offs[key], 1);
        float4 v;
        if (inv) {
            // distinct far-apart sentinel: any pair involving this atom has
            // dist >= ~1e8 > 20 -> masked by the dist test. Finite squares.
            v.x = 1e8f * (float)(i + 1);
            v.y = 0.0f;
            v.z = 0.0f;
            v.w = __int_as_float(0);
        } else {
            v.x = coords[3 * i + 0];
            v.y = coords[3 * i + 1];
            v.z = coords[3 * i + 2];
            v.w = __int_as_float((res_ids[i] << 11) | (t * D_BINS));
        }
        g_sorted[pos] = v;
    }
    // pad region: distinct sentinels (indices >= n, disjoint from invalid-atom
    // sentinels which use original indices < n).
    for (int i = n + tid; i < npad; i += 1024) {
        float4 v;
        v.x = 1e8f * (float)(i + 1);
        v.y = 0.0f;
        v.z = 0.0f;
        v.w = __int_as_float(0);
        g_sorted[i] = v;
    }
}

template <bool DIAG>
__device__ __forceinline__ float tile_accum(float4 mine, int resi, int tbase,
                                            int j0, int p, int q0,
                                            const float* __restrict__ pot) {
    float acc = 0.0f;
#pragma unroll 8
    for (int u = 0; u < JCHUNK; ++u) {
        int jj = j0 + u;
        // wave-uniform address: q0 (block-derived) + jj (loop index).
        // Compiler can scalarize this load (s_load_dwordx4) and the w-unpack
        // below runs on the SALU pipe.
        float4 o = g_sorted[q0 + jj];
        float dx = mine.x - o.x;
        float dy = mine.y - o.y;
        float dz = mine.z - o.z;
        float d2 = __builtin_fmaf(dx, dx, __builtin_fmaf(dy, dy, dz * dz));
        float dist = __builtin_amdgcn_sqrtf(d2) + 1e-8f;

        int packj = __float_as_int(o.w);
        int resj = packj >> 11;          // uniform -> SALU
        int kj21 = packj & 0x7FF;        // key_j * 21, precomputed by sort
        int sep = resi - resj;
        sep = (sep < 0) ? -sep : sep;

        int valid = (sep > 2) & (dist < 20.0f);
        if (DIAG) valid &= ((q0 + jj) > p);

        int k = sep - 1;                 // sep<=2 -> invalid anyway
        k = (k > 5) ? 5 : k;
        int d0i = (int)dist;             // v_cvt saturates for huge sentinels
        d0i = (d0i > 19) ? 19 : d0i;
        float alpha = dist - (float)d0i;

        int idx = k * KSTRIDE + (tbase + kj21 + d0i);
        idx = valid ? idx : 0;
        float e0 = pot[idx];
        float e1 = pot[idx + 1];
        float val = __builtin_fmaf(alpha, e1 - e0, e0) - 2.7f;
        acc += valid ? val : 0.0f;
    }
    return acc;
}

__global__ __launch_bounds__(PAIR_THREADS, 6) void pair_kernel(const float* __restrict__ pot,
                                                               int nt,
                                                               float* __restrict__ out) {
    __shared__ float wsum[PAIR_THREADS / 64];

    int b = blockIdx.x;
    // decode triangular (bi, bj), bi <= bj; row_start(r) = r*nt - r*(r-1)/2
    int bi = (int)((2.0 * nt + 1.0 -
                    sqrt((2.0 * nt + 1.0) * (2.0 * nt + 1.0) - 8.0 * (double)b)) * 0.5);
    if (bi < 0) bi = 0;
    if (bi > nt - 1) bi = nt - 1;
    while ((bi + 1) * nt - ((bi + 1) * bi) / 2 <= b) ++bi;
    while (bi * nt - (bi * (bi - 1)) / 2 > b) --bi;
    int bj = bi + (b - (bi * nt - (bi * (bi - 1)) / 2));

    int tid = threadIdx.x;
    int ilane = tid & (TILE - 1);   // 0..127: which i in the tile
    int chunk = tid >> 7;           // 0..1: which 64-wide slice of j
    int q0 = bj * TILE;
    int p = bi * TILE + ilane;

    float4 mine = g_sorted[p];      // padded: no bounds check

    int packi = __float_as_int(mine.w);
    int resi = packi >> 11;
    int tbase = (packi & 0x7FF) * T_TYPES;  // key_i*21*85 = key_i*1785
    int j0 = chunk * JCHUNK;

    float acc;
    if (bi == bj)
        acc = tile_accum<true>(mine, resi, tbase, j0, p, q0, pot);
    else
        acc = tile_accum<false>(mine, resi, tbase, j0, p, q0, pot);

    // wave (64-lane) reduce, then block reduce, then one atomic
#pragma unroll
    for (int off = 32; off > 0; off >>= 1)
        acc += __shfl_down(acc, off, 64);
    int wave = tid >> 6;
    if ((tid & 63) == 0) wsum[wave] = acc;
    __syncthreads();
    if (tid == 0) {
        float s = wsum[0] + wsum[1] + wsum[2] + wsum[3];
        atomicAdd(out, s);
    }
}

extern "C" void kernel_launch(void* const* d_in, const int* in_sizes, int n_in,
                              void* d_out, int out_size, void* d_ws, size_t ws_size,
                              hipStream_t stream) {
    const float* coords = (const float*)d_in[0];
    const int* res_ids = (const int*)d_in[1];
    const int* types   = (const int*)d_in[2];
    const float* pot   = (const float*)d_in[3];
    int n = in_sizes[1];
    float* out = (float*)d_out;

    int nt = (n + TILE - 1) / TILE;
    int npad = nt * TILE;   // <= MAXN for this problem (N=6144)

    sort_kernel<<<1, 1024, 0, stream>>>(coords, res_ids, types, n, npad, out);

    int nblocks = nt * (nt + 1) / 2;
    pair_kernel<<<nblocks, PAIR_THREADS, 0, stream>>>(pot, nt, out);
}

// Round 3
// 97.393 us; speedup vs baseline: 1.0153x; 1.0153x over previous
//
#include <hip/hip_runtime.h>

// RASP pairwise score, N=6144 atoms, P = N(N-1)/2 pairs.
// pot tensor [K=6, T=85, T=85, D=21] fp32 = 3.64 MB (L1-resident per tile
// after type-sort: tbase wave-uniformized, kj21 wave-uniform).
// R5: parallelize the sort. The single-block sort was the dominant
// controllable cost (~10-20 us latency-bound on ONE CU). Replaced with a
// rank-based 3-dispatch counting sort:
//   k1 hist_kernel   (24 blocks): per-block LDS histogram -> g_part[b][86]
//   k2 scatter_kernel(25 blocks): each block redundantly recomputes
//       global key offsets + its own inter-block row-prefix from g_part
//       (LDS-broadcast reads), then scatters its 256 atoms with
//       block-local LDS atomics. Within-key order is arbitrary ->
//       permutation-invariant sum, still exact.
//   k3 pair_kernel: unchanged from R4 (verified absmax 0.0).
// Measurement note: ~82 us of the timed window is two unconditional 268 MB
// harness poison fills (41 us each, present in all rounds regardless of
// whether d_ws is touched). Controllable portion is only ~10-16 us.

#define T_TYPES 85
#define D_BINS 21
#define KSTRIDE (T_TYPES * T_TYPES * D_BINS)  // 151725
#define NKEYS 86                              // 85 types + 1 invalid bin
#define TILE 128
#define PAIR_THREADS 256
#define JCHUNK 64                             // TILE / (PAIR_THREADS/TILE)
#define MAXN 8192
#define MAXHB 32                              // max hist/scatter blocks (n <= 8192)

__device__ float4 g_sorted[MAXN];
__device__ int g_part[MAXHB][NKEYS];

// k1: per-block partial histograms (256 atoms each); block 0 zeros out.
__global__ __launch_bounds__(256) void hist_kernel(const int* __restrict__ types,
                                                   int n, float* __restrict__ out) {
    __shared__ int hist[NKEYS];
    int tid = threadIdx.x, b = blockIdx.x;
    if (tid < NKEYS) hist[tid] = 0;
    if (b == 0 && tid == 0) *out = 0.0f;
    __syncthreads();
    int i = b * 256 + tid;
    if (i < n) {
        int t = types[i];
        atomicAdd(&hist[(t < 0) ? (NKEYS - 1) : t], 1);
    }
    __syncthreads();
    if (tid < NKEYS) g_part[b][tid] = hist[tid];
}

// k2: rank-based scatter. Each block recomputes the global key offsets and
// its own inter-block prefix (no global atomics, no extra sync kernel),
// then places its 256 atoms. Tail blocks write pad sentinels.
__global__ __launch_bounds__(256) void scatter_kernel(const float* __restrict__ coords,
                                                      const int* __restrict__ res_ids,
                                                      const int* __restrict__ types,
                                                      int n, int nhb, int npad) {
    __shared__ int base[NKEYS];  // becomes: my block's next write pos per key
    __shared__ int tot[NKEYS];
    int tid = threadIdx.x, b = blockIdx.x;
    if (tid < NKEYS) {
        int t = 0, mine = 0;
        for (int bb = 0; bb < nhb; ++bb) {
            int h = g_part[bb][tid];   // coalesced across tid
            t += h;
            mine += (bb < b) ? h : 0;
        }
        tot[tid] = t;
        base[tid] = mine;              // row-prefix within this key
    }
    __syncthreads();
    if (tid < NKEYS) {
        int s = 0;
#pragma unroll 1
        for (int k = 0; k < NKEYS; ++k) {
            int tk = tot[k];           // LDS broadcast
            s += (k < tid) ? tk : 0;
        }
        base[tid] += s;                // + exclusive key offset
    }
    __syncthreads();
    int i = b * 256 + tid;
    if (i < n) {
        int t = types[i];
        int inv = (t < 0);
        int key = inv ? (NKEYS - 1) : t;
        int pos = atomicAdd(&base[key], 1);  // block-local LDS atomic
        float4 v;
        if (inv) {
            // distinct far-apart sentinel: any pair involving this atom has
            // dist >= ~1e8 > 20 -> masked by the dist test. Finite squares.
            v.x = 1e8f * (float)(i + 1);
            v.y = 0.0f;
            v.z = 0.0f;
            v.w = __int_as_float(0);
        } else {
            v.x = coords[3 * i + 0];
            v.y = coords[3 * i + 1];
            v.z = coords[3 * i + 2];
            v.w = __int_as_float((res_ids[i] << 11) | (t * D_BINS));
        }
        g_sorted[pos] = v;
    } else if (i < npad) {
        // pad region: distinct sentinels (indices >= n, disjoint from
        // invalid-atom sentinels which use original indices < n).
        float4 v;
        v.x = 1e8f * (float)(i + 1);
        v.y = 0.0f;
        v.z = 0.0f;
        v.w = __int_as_float(0);
        g_sorted[i] = v;
    }
}

template <bool DIAG>
__device__ __forceinline__ float tile_accum(float4 mine, int resi, int tbase,
                                            int j0, int p, int q0,
                                            const float* __restrict__ pot) {
    float acc = 0.0f;
#pragma unroll 8
    for (int u = 0; u < JCHUNK; ++u) {
        int jj = j0 + u;
        // wave-uniform address (block base + loop index) -> scalarizable load
        float4 o = g_sorted[q0 + jj];
        float dx = mine.x - o.x;
        float dy = mine.y - o.y;
        float dz = mine.z - o.z;
        float d2 = __builtin_fmaf(dx, dx, __builtin_fmaf(dy, dy, dz * dz));
        float dist = __builtin_amdgcn_sqrtf(d2) + 1e-8f;

        int packj = __float_as_int(o.w);
        int resj = packj >> 11;          // uniform -> SALU
        int kj21 = packj & 0x7FF;        // key_j * 21, precomputed by sort
        int sep = resi - resj;
        sep = (sep < 0) ? -sep : sep;

        int valid = (sep > 2) & (dist < 20.0f);
        if (DIAG) valid &= ((q0 + jj) > p);

        int k = sep - 1;                 // sep<=2 -> invalid anyway
        k = (k > 5) ? 5 : k;
        int d0i = (int)dist;             // v_cvt saturates for huge sentinels
        d0i = (d0i > 19) ? 19 : d0i;
        float alpha = dist - (float)d0i;

        int idx = k * KSTRIDE + (tbase + kj21 + d0i);
        idx = valid ? idx : 0;
        float e0 = pot[idx];
        float e1 = pot[idx + 1];
        float val = __builtin_fmaf(alpha, e1 - e0, e0) - 2.7f;
        acc += valid ? val : 0.0f;
    }
    return acc;
}

__global__ __launch_bounds__(PAIR_THREADS, 6) void pair_kernel(const float* __restrict__ pot,
                                                               int nt,
                                                               float* __restrict__ out) {
    __shared__ float wsum[PAIR_THREADS / 64];

    int b = blockIdx.x;
    // decode triangular (bi, bj), bi <= bj; row_start(r) = r*nt - r*(r-1)/2
    int bi = (int)((2.0 * nt + 1.0 -
                    sqrt((2.0 * nt + 1.0) * (2.0 * nt + 1.0) - 8.0 * (double)b)) * 0.5);
    if (bi < 0) bi = 0;
    if (bi > nt - 1) bi = nt - 1;
    while ((bi + 1) * nt - ((bi + 1) * bi) / 2 <= b) ++bi;
    while (bi * nt - (bi * (bi - 1)) / 2 > b) --bi;
    int bj = bi + (b - (bi * nt - (bi * (bi - 1)) / 2));

    int tid = threadIdx.x;
    int ilane = tid & (TILE - 1);   // 0..127: which i in the tile
    int chunk = tid >> 7;           // 0..1: which 64-wide slice of j
    int q0 = bj * TILE;
    int p = bi * TILE + ilane;

    float4 mine = g_sorted[p];      // padded: no bounds check

    int packi = __float_as_int(mine.w);
    int resi = packi >> 11;
    int tbase = (packi & 0x7FF) * T_TYPES;  // key_i*21*85 = key_i*1785
    int j0 = chunk * JCHUNK;

    float acc;
    if (bi == bj)
        acc = tile_accum<true>(mine, resi, tbase, j0, p, q0, pot);
    else
        acc = tile_accum<false>(mine, resi, tbase, j0, p, q0, pot);

    // wave (64-lane) reduce, then block reduce, then one atomic
#pragma unroll
    for (int off = 32; off > 0; off >>= 1)
        acc += __shfl_down(acc, off, 64);
    int wave = tid >> 6;
    if ((tid & 63) == 0) wsum[wave] = acc;
    __syncthreads();
    if (tid == 0) {
        float s = wsum[0] + wsum[1] + wsum[2] + wsum[3];
        atomicAdd(out, s);
    }
}

extern "C" void kernel_launch(void* const* d_in, const int* in_sizes, int n_in,
                              void* d_out, int out_size, void* d_ws, size_t ws_size,
                              hipStream_t stream) {
    const float* coords = (const float*)d_in[0];
    const int* res_ids = (const int*)d_in[1];
    const int* types   = (const int*)d_in[2];
    const float* pot   = (const float*)d_in[3];
    int n = in_sizes[1];
    float* out = (float*)d_out;

    int nt = (n + TILE - 1) / TILE;
    int npad = nt * TILE;                 // <= MAXN for this problem (N=6144)
    int nhb = (n + 255) / 256;            // 24 histogram blocks
    int npadb = (npad + 255) / 256;       // 25 scatter blocks (incl. pad tail)

    hist_kernel<<<nhb, 256, 0, stream>>>(types, n, out);
    scatter_kernel<<<npadb, 256, 0, stream>>>(coords, res_ids, types, n, nhb, npad);

    int nblocks = nt * (nt + 1) / 2;
    pair_kernel<<<nblocks, PAIR_THREADS, 0, stream>>>(pot, nt, out);
}

// Round 4
// 88.638 us; speedup vs baseline: 1.1156x; 1.0988x over previous
//
#include <hip/hip_runtime.h>

// RASP pairwise score, N=6144 atoms, P = N(N-1)/2 pairs.
// pot tensor [K=6, T=85, T=85, D=21] fp32 = 3.64 MB (L2/L3-resident; per-tile
// gather footprint ~KBs after the type-sort makes tbase near-wave-uniform).
//
// R6: recombination of the per-round winners (rounds were confounded):
//  - pair kernel back to R2's 512-thread / LDS-jtile structure (8 waves/block
//    hides the gather chain; LDS tile pays the j-fetch once per tile instead
//    of an SMEM load on every iteration's critical path — the R4/R5
//    scalar-load variant was ~4 us slower).
//  - keeps R3's inner-loop diet: sentinel coords for invalid/pad atoms (the
//    dist<20 test subsumes type-validity and bounds checks), w packs
//    res<<11 | key*21 (no per-pair mul), diagonal-only q>p via template.
//  - keeps R5's parallel rank-based 2-dispatch counting sort (no global
//    atomics; within-key order arbitrary -> sum is permutation-invariant).
//
// Measurement floor note (R2-R5 evidence): the timed window unconditionally
// contains two 268 MB harness poison fills (~41 us each, 82-83% of HBM peak,
// present whether or not d_ws is touched). Controllable kernel time is the
// ~9-16 us residual; this round minimizes that residual.

#define T_TYPES 85
#define D_BINS 21
#define KSTRIDE (T_TYPES * T_TYPES * D_BINS)  // 151725
#define NKEYS 86                              // 85 types + 1 invalid bin
#define TILE 128
#define PAIR_THREADS 512
#define JCHUNK 32                             // TILE / (PAIR_THREADS/TILE)
#define MAXN 8192
#define MAXHB 32                              // max hist/scatter blocks

__device__ float4 g_sorted[MAXN];
__device__ int g_part[MAXHB][NKEYS];

// k1: per-block partial histograms (256 atoms each); block 0 zeros out.
__global__ __launch_bounds__(256) void hist_kernel(const int* __restrict__ types,
                                                   int n, float* __restrict__ out) {
    __shared__ int hist[NKEYS];
    int tid = threadIdx.x, b = blockIdx.x;
    if (tid < NKEYS) hist[tid] = 0;
    if (b == 0 && tid == 0) *out = 0.0f;
    __syncthreads();
    int i = b * 256 + tid;
    if (i < n) {
        int t = types[i];
        atomicAdd(&hist[(t < 0) ? (NKEYS - 1) : t], 1);
    }
    __syncthreads();
    if (tid < NKEYS) g_part[b][tid] = hist[tid];
}

// k2: rank-based scatter. Each block redundantly recomputes global key
// offsets + its own inter-block row-prefix from g_part (LDS-broadcast
// reads), then places its 256 atoms with block-local LDS atomics.
__global__ __launch_bounds__(256) void scatter_kernel(const float* __restrict__ coords,
                                                      const int* __restrict__ res_ids,
                                                      const int* __restrict__ types,
                                                      int n, int nhb, int npad) {
    __shared__ int base[NKEYS];  // becomes: my block's next write pos per key
    __shared__ int tot[NKEYS];
    int tid = threadIdx.x, b = blockIdx.x;
    if (tid < NKEYS) {
        int t = 0, mine = 0;
        for (int bb = 0; bb < nhb; ++bb) {
            int h = g_part[bb][tid];   // coalesced across tid
            t += h;
            mine += (bb < b) ? h : 0;
        }
        tot[tid] = t;
        base[tid] = mine;              // row-prefix within this key
    }
    __syncthreads();
    if (tid < NKEYS) {
        int s = 0;
#pragma unroll 1
        for (int k = 0; k < NKEYS; ++k) {
            int tk = tot[k];           // LDS broadcast
            s += (k < tid) ? tk : 0;
        }
        base[tid] += s;                // + exclusive key offset
    }
    __syncthreads();
    int i = b * 256 + tid;
    if (i < n) {
        int t = types[i];
        int inv = (t < 0);
        int key = inv ? (NKEYS - 1) : t;
        int pos = atomicAdd(&base[key], 1);  // block-local LDS atomic
        float4 v;
        if (inv) {
            // distinct far-apart sentinel: any pair involving this atom has
            // dist >= ~1e8 > 20 -> masked by the dist test. Finite squares.
            v.x = 1e8f * (float)(i + 1);
            v.y = 0.0f;
            v.z = 0.0f;
            v.w = __int_as_float(0);
        } else {
            v.x = coords[3 * i + 0];
            v.y = coords[3 * i + 1];
            v.z = coords[3 * i + 2];
            v.w = __int_as_float((res_ids[i] << 11) | (t * D_BINS));
        }
        g_sorted[pos] = v;
    } else if (i < npad) {
        // pad region: distinct sentinels (indices >= n, disjoint from
        // invalid-atom sentinels which use original indices < n).
        float4 v;
        v.x = 1e8f * (float)(i + 1);
        v.y = 0.0f;
        v.z = 0.0f;
        v.w = __int_as_float(0);
        g_sorted[i] = v;
    }
}

template <bool DIAG>
__device__ __forceinline__ float tile_accum(const float4* __restrict__ jt,
                                            float4 mine, int resi, int tbase,
                                            int j0, int p, int q0,
                                            const float* __restrict__ pot) {
    float acc = 0.0f;
#pragma unroll 8
    for (int u = 0; u < JCHUNK; ++u) {
        int jj = j0 + u;
        float4 o = jt[jj];  // jj uniform per wave -> LDS broadcast, no conflict
        float dx = mine.x - o.x;
        float dy = mine.y - o.y;
        float dz = mine.z - o.z;
        float d2 = __builtin_fmaf(dx, dx, __builtin_fmaf(dy, dy, dz * dz));
        float dist = __builtin_amdgcn_sqrtf(d2) + 1e-8f;

        int packj = __float_as_int(o.w);
        int resj = packj >> 11;
        int kj21 = packj & 0x7FF;        // key_j * 21, precomputed by sort
        int sep = resi - resj;
        sep = (sep < 0) ? -sep : sep;

        int valid = (sep > 2) & (dist < 20.0f);
        if (DIAG) valid &= ((q0 + jj) > p);

        int k = sep - 1;                 // sep<=2 -> invalid anyway
        k = (k > 5) ? 5 : k;
        int d0i = (int)dist;             // v_cvt saturates for huge sentinels
        d0i = (d0i > 19) ? 19 : d0i;
        float alpha = dist - (float)d0i;

        int idx = k * KSTRIDE + (tbase + kj21 + d0i);
        idx = valid ? idx : 0;
        float e0 = pot[idx];
        float e1 = pot[idx + 1];
        float val = __builtin_fmaf(alpha, e1 - e0, e0) - 2.7f;
        acc += valid ? val : 0.0f;
    }
    return acc;
}

__global__ __launch_bounds__(PAIR_THREADS) void pair_kernel(const float* __restrict__ pot,
                                                            int nt,
                                                            float* __restrict__ out) {
    __shared__ float4 jtile[TILE];
    __shared__ float wsum[PAIR_THREADS / 64];

    int b = blockIdx.x;
    // decode triangular (bi, bj), bi <= bj; row_start(r) = r*nt - r*(r-1)/2
    int bi = (int)((2.0 * nt + 1.0 -
                    sqrt((2.0 * nt + 1.0) * (2.0 * nt + 1.0) - 8.0 * (double)b)) * 0.5);
    if (bi < 0) bi = 0;
    if (bi > nt - 1) bi = nt - 1;
    while ((bi + 1) * nt - ((bi + 1) * bi) / 2 <= b) ++bi;
    while (bi * nt - (bi * (bi - 1)) / 2 > b) --bi;
    int bj = bi + (b - (bi * nt - (bi * (bi - 1)) / 2));

    int tid = threadIdx.x;
    int ilane = tid & (TILE - 1);   // 0..127: which i in the tile
    int chunk = tid >> 7;           // 0..3: which 32-wide slice of j
    int q0 = bj * TILE;
    int p = bi * TILE + ilane;

    if (tid < TILE) jtile[tid] = g_sorted[q0 + tid];  // padded: no bounds check
    float4 mine = g_sorted[p];
    __syncthreads();

    int packi = __float_as_int(mine.w);
    int resi = packi >> 11;
    int tbase = (packi & 0x7FF) * T_TYPES;  // key_i*21*85 = key_i*1785
    int j0 = chunk * JCHUNK;

    float acc;
    if (bi == bj)
        acc = tile_accum<true>(jtile, mine, resi, tbase, j0, p, q0, pot);
    else
        acc = tile_accum<false>(jtile, mine, resi, tbase, j0, p, q0, pot);

    // wave (64-lane) reduce, then block reduce, then one atomic
#pragma unroll
    for (int off = 32; off > 0; off >>= 1)
        acc += __shfl_down(acc, off, 64);
    int wave = tid >> 6;
    if ((tid & 63) == 0) wsum[wave] = acc;
    __syncthreads();
    if (tid == 0) {
        float s = 0.f;
#pragma unroll
        for (int w = 0; w < PAIR_THREADS / 64; ++w) s += wsum[w];
        atomicAdd(out, s);
    }
}

extern "C" void kernel_launch(void* const* d_in, const int* in_sizes, int n_in,
                              void* d_out, int out_size, void* d_ws, size_t ws_size,
                              hipStream_t stream) {
    const float* coords = (const float*)d_in[0];
    const int* res_ids = (const int*)d_in[1];
    const int* types   = (const int*)d_in[2];
    const float* pot   = (const float*)d_in[3];
    int n = in_sizes[1];
    float* out = (float*)d_out;

    int nt = (n + TILE - 1) / TILE;
    int npad = nt * TILE;                 // <= MAXN for this problem (N=6144)
    int nhb = (n + 255) / 256;            // 24 histogram blocks
    int npadb = (npad + 255) / 256;       // 25 scatter blocks (incl. pad tail)

    hist_kernel<<<nhb, 256, 0, stream>>>(types, n, out);
    scatter_kernel<<<npadb, 256, 0, stream>>>(coords, res_ids, types, n, nhb, npad);

    int nblocks = nt * (nt + 1) / 2;
    pair_kernel<<<nblocks, PAIR_THREADS, 0, stream>>>(pot, nt, out);
}